// Round 11
// baseline (1244.759 us; speedup 1.0000x reference)
//
#include <hip/hip_runtime.h>

#define HD 128
#define BP(n) ((n) + (((n) >> 5) << 2))

constexpr int N_ATOMS = 20000;
constexpr int N_EDGES = 320000;
constexpr int NLAY   = 4;
constexpr int NMOL   = 200;
constexpr float FCUT  = 5.0f;
constexpr float DELTA = FCUT / 127.0f;
constexpr float GCOEFF = -0.5f / (DELTA * DELTA);
constexpr float PI_F  = 3.14159265358979323846f;
constexpr float LN2F  = 0.6931471805599453f;

__device__ __forceinline__ float sspf(float x) {
  return fmaxf(x, 0.0f) + log1pf(expf(-fabsf(x))) - LN2F;
}
__device__ __forceinline__ float sigmf(float x) {
  return 1.0f / (1.0f + expf(-x));
}

__device__ __forceinline__ unsigned bfpack(float a, float b) {
  unsigned ua = __float_as_uint(a);
  unsigned ub = __float_as_uint(b);
  ua = (ua + 0x7FFFu + ((ua >> 16) & 1u)) >> 16;
  ub = (ub + 0x7FFFu + ((ub >> 16) & 1u)) >> 16;
  return (ub << 16) | ua;
}
__device__ __forceinline__ float bflo(unsigned p) { return __uint_as_float(p << 16); }
__device__ __forceinline__ float bfhi(unsigned p) { return __uint_as_float(p & 0xFFFF0000u); }

// ------------------------------------------------------------------
// small elementwise kernels
// ------------------------------------------------------------------

__global__ __launch_bounds__(256) void geom_k(
    const float* __restrict__ pos, const int* __restrict__ row,
    const int* __restrict__ col, float* __restrict__ dist)
{
  int e = blockIdx.x * 256 + threadIdx.x;
  if (e >= N_EDGES) return;
  int r = row[e], c = col[e];
  float dx = pos[3*r+0] - pos[3*c+0];
  float dy = pos[3*r+1] - pos[3*c+1];
  float dz = pos[3*r+2] - pos[3*c+2];
  dist[e] = sqrtf(dx*dx + dy*dy + dz*dz);
}

__global__ __launch_bounds__(256) void h0_k(
    const float* __restrict__ emb, const int* __restrict__ z,
    float* __restrict__ h0)
{
  int i = blockIdx.x * 256 + threadIdx.x;
  if (i >= N_ATOMS * HD) return;
  int n = i >> 7, k = i & 127;
  h0[i] = emb[z[n] * HD + k];
}

// ------------------------------------------------------------------
// CSR build
// ------------------------------------------------------------------
__global__ __launch_bounds__(256) void hist_k(
    const int* __restrict__ idx, int* __restrict__ cnt)
{
  int e = blockIdx.x * 256 + threadIdx.x;
  if (e >= N_EDGES) return;
  atomicAdd(&cnt[idx[e]], 1);
}

__global__ __launch_bounds__(256) void scan_k(
    const int* __restrict__ cnt, int* __restrict__ ptr)
{
  constexpr int CH = 79;
  __shared__ int part[256];
  int t = threadIdx.x;
  int base = t * CH;
  int s = 0;
  for (int i = 0; i < CH; i++) {
    int idx = base + i;
    if (idx < N_ATOMS) s += cnt[idx];
  }
  part[t] = s;
  __syncthreads();
  for (int off = 1; off < 256; off <<= 1) {
    int u = (t >= off) ? part[t - off] : 0;
    __syncthreads();
    part[t] += u;
    __syncthreads();
  }
  int run = part[t] - s;
  for (int i = 0; i < CH; i++) {
    int idx = base + i;
    if (idx > N_ATOMS) break;
    ptr[idx] = run;
    if (idx < N_ATOMS) run += cnt[idx];
  }
}

__global__ __launch_bounds__(256) void scat_row_k(
    const int* __restrict__ row, const int* __restrict__ col,
    const float* __restrict__ dist, int* __restrict__ cur,
    int* __restrict__ rother, float* __restrict__ rdist,
    int* __restrict__ slotof)
{
  int e = blockIdx.x * 256 + threadIdx.x;
  if (e >= N_EDGES) return;
  int p = atomicAdd(&cur[row[e]], 1);
  rother[p] = col[e];
  rdist[p] = dist[e];
  slotof[e] = p;
}

__global__ __launch_bounds__(256) void scat_col_k(
    const int* __restrict__ row, const int* __restrict__ col,
    const float* __restrict__ dist, int* __restrict__ cur,
    int* __restrict__ cother, float* __restrict__ cdist,
    const int* __restrict__ slotof, int* __restrict__ cslot)
{
  int e = blockIdx.x * 256 + threadIdx.x;
  if (e >= N_EDGES) return;
  int p = atomicAdd(&cur[col[e]], 1);
  cother[p] = row[e];
  cdist[p] = dist[e];
  cslot[p] = slotof[e];
}

// ------------------------------------------------------------------
// table build
// ------------------------------------------------------------------
__global__ __launch_bounds__(256) void nodeA_k(
    float* __restrict__ A, float* __restrict__ dA, int nnode, float hstep)
{
  int i = blockIdx.x * 256 + threadIdx.x;
  if (i >= nnode * HD) return;
  int node = i >> 7, g = i & 127;
  float d = (float)node * hstep;
  float t = d - (float)g * DELTA;
  float a = expf(GCOEFF * t * t);
  A[i] = a;
  dA[i] = a * 2.0f * GCOEFF * t;
}

__global__ __launch_bounds__(256) void nodeact_k(
    const float* __restrict__ t1, const float* __restrict__ u,
    float* __restrict__ s, float* __restrict__ sp, int total)
{
  int i = blockIdx.x * 256 + threadIdx.x;
  if (i >= total) return;
  float x = t1[i];
  s[i] = sspf(x);
  sp[i] = sigmf(x) * u[i];
}

__global__ __launch_bounds__(256) void nodecomb_k(
    const float* __restrict__ P0, const float* __restrict__ D0,
    unsigned* __restrict__ T, int nnode, float hstep)
{
  int i = blockIdx.x * 256 + threadIdx.x;
  int total = NLAY * nnode * HD;
  if (i >= total) return;
  int rem = i % (nnode * HD);
  int node = rem >> 7;
  float d = (float)node * hstep;
  float C  = 0.5f * cosf(d * (PI_F / FCUT)) + 0.5f;
  float Cp = -0.5f * sinf(d * (PI_F / FCUT)) * (PI_F / FCUT);
  float p = P0[i], q = D0[i];
  T[i] = bfpack(p * C, q * C + p * Cp);
}

// ------------------------------------------------------------------
// N-GEMM, 64x32 tile, grid (ceil(M/64), 4): high occupancy.
// C[:, n0g:n0g+32] = epi( op_a(A)[M,128] @ B(^T) + bias )
// MODE_A: 0 plain, 1 ssp on load
// EPI: 0 none, 1 +EP1, 2 acc*sigm(EP1)
// OB : bf16-packed output (pairs)
// ------------------------------------------------------------------
template<int MODE_A, int EPI, bool BT, bool OB>
__global__ __launch_bounds__(256) void gemm32_k(
    const float* __restrict__ A, const float* __restrict__ B,
    const float* __restrict__ bias, const float* __restrict__ EP1,
    float* __restrict__ C, int M)
{
  __shared__ float As[16][68];
  __shared__ float Bs[16][36];
  int t = threadIdx.x;
  int tx = t & 7;          // 8 col groups x4
  int ty = t >> 3;         // 32 row groups x2
  int m0 = blockIdx.x * 64;
  int n0g = blockIdx.y * 32;

  float acc[2][4];
#pragma unroll
  for (int r = 0; r < 2; r++)
#pragma unroll
    for (int c = 0; c < 4; c++) acc[r][c] = 0.0f;

  for (int k0 = 0; k0 < HD; k0 += 16) {
    {
      int rrow = t >> 2;
      int kg = (t & 3) * 4;
      int gm = m0 + rrow;
      float4 av = make_float4(0.f, 0.f, 0.f, 0.f);
      if (gm < M) av = *(const float4*)(A + (size_t)gm * HD + k0 + kg);
      if (MODE_A == 1) { av.x = sspf(av.x); av.y = sspf(av.y); av.z = sspf(av.z); av.w = sspf(av.w); }
      As[kg+0][rrow] = av.x; As[kg+1][rrow] = av.y;
      As[kg+2][rrow] = av.z; As[kg+3][rrow] = av.w;
    }
    if (t < 128) {
      if (!BT) {
        int kk = t >> 3;            // 0..15
        int n4 = (t & 7) * 4;       // 0..28
        float4 bv = *(const float4*)(B + (size_t)(k0 + kk) * HD + n0g + n4);
        *(float4*)&Bs[kk][n4] = bv;
      } else {
        int n = t >> 2;             // 0..31
        int kg = (t & 3) * 4;
        float4 bv = *(const float4*)(B + (size_t)(n0g + n) * HD + k0 + kg);
        Bs[kg+0][n] = bv.x; Bs[kg+1][n] = bv.y;
        Bs[kg+2][n] = bv.z; Bs[kg+3][n] = bv.w;
      }
    }
    __syncthreads();
#pragma unroll
    for (int kk = 0; kk < 16; kk++) {
      float a0 = As[kk][ty * 2];
      float a1 = As[kk][ty * 2 + 1];
      float4 b4 = *(const float4*)&Bs[kk][tx * 4];
      acc[0][0] = fmaf(a0, b4.x, acc[0][0]);
      acc[0][1] = fmaf(a0, b4.y, acc[0][1]);
      acc[0][2] = fmaf(a0, b4.z, acc[0][2]);
      acc[0][3] = fmaf(a0, b4.w, acc[0][3]);
      acc[1][0] = fmaf(a1, b4.x, acc[1][0]);
      acc[1][1] = fmaf(a1, b4.y, acc[1][1]);
      acc[1][2] = fmaf(a1, b4.z, acc[1][2]);
      acc[1][3] = fmaf(a1, b4.w, acc[1][3]);
    }
    __syncthreads();
  }

  int nc = n0g + tx * 4;
  float bv4[4];
#pragma unroll
  for (int c = 0; c < 4; c++) bv4[c] = bias ? bias[nc + c] : 0.0f;
#pragma unroll
  for (int r = 0; r < 2; r++) {
    int gm = m0 + ty * 2 + r;
    if (gm >= M) continue;
    float out[4];
    if (EPI == 2) {
      float4 e = *(const float4*)(EP1 + (size_t)gm * HD + nc);
      out[0] = acc[r][0] * sigmf(e.x);
      out[1] = acc[r][1] * sigmf(e.y);
      out[2] = acc[r][2] * sigmf(e.z);
      out[3] = acc[r][3] * sigmf(e.w);
    } else {
#pragma unroll
      for (int c = 0; c < 4; c++) out[c] = acc[r][c] + bv4[c];
      if (EPI == 1) {
        float4 e = *(const float4*)(EP1 + (size_t)gm * HD + nc);
        out[0] += e.x; out[1] += e.y; out[2] += e.z; out[3] += e.w;
      }
    }
    if (OB) {
      uint2 pk;
      pk.x = bfpack(out[0], out[1]);
      pk.y = bfpack(out[2], out[3]);
      *(uint2*)((unsigned*)C + (size_t)gm * 64 + (nc >> 1)) = pk;
    } else {
      *(float4*)(C + (size_t)gm * HD + nc) = *(float4*)&out[0];
    }
  }
}

// batched plain GEMM for table build (64-row, 128-col; small grid, run once)
__global__ __launch_bounds__(256) void gemm128b_k(
    const float* __restrict__ A, size_t astride,
    const float* __restrict__ B, size_t bstride,
    const float* __restrict__ bias, size_t biasstride,
    float* __restrict__ C, size_t cstride, int M)
{
  int l = blockIdx.y;
  A += (size_t)l * astride;
  B += (size_t)l * bstride;
  if (bias) bias += (size_t)l * biasstride;
  C += (size_t)l * cstride;

  __shared__ float As[16][68];
  __shared__ float Bs[16][144];
  int t = threadIdx.x;
  int tx = t & 15, ty = t >> 4;
  int m0 = blockIdx.x * 64;

  float acc[4][8];
#pragma unroll
  for (int r = 0; r < 4; r++)
#pragma unroll
    for (int c = 0; c < 8; c++) acc[r][c] = 0.0f;

  for (int k0 = 0; k0 < HD; k0 += 16) {
    {
      int rrow = t >> 2;
      int kg = (t & 3) * 4;
      int gm = m0 + rrow;
      float4 av = make_float4(0.f, 0.f, 0.f, 0.f);
      if (gm < M) av = *(const float4*)(A + (size_t)gm * HD + k0 + kg);
      As[kg+0][rrow] = av.x; As[kg+1][rrow] = av.y;
      As[kg+2][rrow] = av.z; As[kg+3][rrow] = av.w;
    }
#pragma unroll
    for (int it = 0; it < 2; it++) {
      int f4 = t + it * 256;
      int kk = f4 >> 5;
      int n4 = (f4 & 31) * 4;
      float4 bv = *(const float4*)(B + (size_t)(k0 + kk) * HD + n4);
      *(float4*)&Bs[kk][BP(n4)] = bv;
    }
    __syncthreads();
    int p0 = BP(tx * 8);
#pragma unroll
    for (int kk = 0; kk < 16; kk++) {
      float a[4], b[8];
#pragma unroll
      for (int r = 0; r < 4; r++) a[r] = As[kk][ty * 4 + r];
#pragma unroll
      for (int c = 0; c < 8; c++) b[c] = Bs[kk][p0 + c];
#pragma unroll
      for (int r = 0; r < 4; r++)
#pragma unroll
        for (int c = 0; c < 8; c++) acc[r][c] = fmaf(a[r], b[c], acc[r][c]);
    }
    __syncthreads();
  }

  int n0 = tx * 8;
  float bv[8];
#pragma unroll
  for (int c = 0; c < 8; c++) bv[c] = bias ? bias[n0 + c] : 0.0f;
#pragma unroll
  for (int r = 0; r < 4; r++) {
    int gm = m0 + ty * 4 + r;
    if (gm >= M) continue;
    float out[8];
#pragma unroll
    for (int c = 0; c < 8; c++) out[c] = acc[r][c] + bv[c];
    *(float4*)(C + (size_t)gm * HD + n0)     = *(float4*)&out[0];
    *(float4*)(C + (size_t)gm * HD + n0 + 4) = *(float4*)&out[4];
  }
}

// ------------------------------------------------------------------
// forward gather: agg[a] = sum_in hx[src] * P(d); linear interp
// ------------------------------------------------------------------
__global__ __launch_bounds__(256) void gath_fwd_k(
    const int* __restrict__ cptr, const int* __restrict__ cother,
    const float* __restrict__ cdist, const unsigned* __restrict__ T,
    const unsigned* __restrict__ hx, float* __restrict__ agg,
    float inv_h)
{
  int a = blockIdx.x * 4 + (threadIdx.x >> 6);
  if (a >= N_ATOMS) return;
  int half = (threadIdx.x >> 5) & 1;
  int l32 = threadIdx.x & 31;
  int ch = l32 * 4;
  int beg = cptr[a], end = cptr[a + 1];
  float s0 = 0.f, s1 = 0.f, s2 = 0.f, s3 = 0.f;
  for (int j = beg + half; j < end; j += 2) {
    int other = cother[j];
    float d = cdist[j];
    float fi = d * inv_h;
    int i0 = (int)fi;
    float t = fi - (float)i0;
    const unsigned* tp = T + (size_t)i0 * HD + ch;
    uint4 q0 = *(const uint4*)(tp);
    uint4 q1 = *(const uint4*)(tp + HD);
    uint2 hp = *(const uint2*)(hx + (size_t)other * 64 + l32 * 2);
    float v0 = fmaf(t, bflo(q1.x) - bflo(q0.x), bflo(q0.x));
    float v1 = fmaf(t, bflo(q1.y) - bflo(q0.y), bflo(q0.y));
    float v2 = fmaf(t, bflo(q1.z) - bflo(q0.z), bflo(q0.z));
    float v3 = fmaf(t, bflo(q1.w) - bflo(q0.w), bflo(q0.w));
    s0 = fmaf(bflo(hp.x), v0, s0);
    s1 = fmaf(bfhi(hp.x), v1, s1);
    s2 = fmaf(bflo(hp.y), v2, s2);
    s3 = fmaf(bfhi(hp.y), v3, s3);
  }
  s0 += __shfl_xor(s0, 32, 64);
  s1 += __shfl_xor(s1, 32, 64);
  s2 += __shfl_xor(s2, 32, 64);
  s3 += __shfl_xor(s3, 32, 64);
  if (half == 0)
    *(float4*)(agg + (size_t)a * HD + ch) = make_float4(s0, s1, s2, s3);
}

// ------------------------------------------------------------------
// backward gather: dhx + ddslot, linear interp
// ------------------------------------------------------------------
__global__ __launch_bounds__(256) void gath_bwd_k(
    const int* __restrict__ rptr, const int* __restrict__ rother,
    const float* __restrict__ rdist, const unsigned* __restrict__ T,
    const unsigned* __restrict__ dagg, const unsigned* __restrict__ hx,
    float* __restrict__ dhx, float* __restrict__ ddslot,
    float inv_h)
{
  int a = blockIdx.x * 4 + (threadIdx.x >> 6);
  if (a >= N_ATOMS) return;
  int half = (threadIdx.x >> 5) & 1;
  int l32 = threadIdx.x & 31;
  int ch = l32 * 4;
  int beg = rptr[a], end = rptr[a + 1];
  uint2 hp = *(const uint2*)(hx + (size_t)a * 64 + l32 * 2);
  float h0 = bflo(hp.x), h1 = bfhi(hp.x), h2 = bflo(hp.y), h3 = bfhi(hp.y);
  float s0 = 0.f, s1 = 0.f, s2 = 0.f, s3 = 0.f;
  for (int j = beg + half; j < end; j += 2) {
    int other = rother[j];
    float d = rdist[j];
    float fi = d * inv_h;
    int i0 = (int)fi;
    float t = fi - (float)i0;
    const unsigned* tp = T + (size_t)i0 * HD + ch;
    uint4 q0 = *(const uint4*)(tp);
    uint4 q1 = *(const uint4*)(tp + HD);
    uint2 dp = *(const uint2*)(dagg + (size_t)other * 64 + l32 * 2);
    float da0 = bflo(dp.x), da1 = bfhi(dp.x), da2 = bflo(dp.y), da3 = bfhi(dp.y);
    float v0 = fmaf(t, bflo(q1.x) - bflo(q0.x), bflo(q0.x));
    float v1 = fmaf(t, bflo(q1.y) - bflo(q0.y), bflo(q0.y));
    float v2 = fmaf(t, bflo(q1.z) - bflo(q0.z), bflo(q0.z));
    float v3 = fmaf(t, bflo(q1.w) - bflo(q0.w), bflo(q0.w));
    float g0 = fmaf(t, bfhi(q1.x) - bfhi(q0.x), bfhi(q0.x));
    float g1 = fmaf(t, bfhi(q1.y) - bfhi(q0.y), bfhi(q0.y));
    float g2 = fmaf(t, bfhi(q1.z) - bfhi(q0.z), bfhi(q0.z));
    float g3 = fmaf(t, bfhi(q1.w) - bfhi(q0.w), bfhi(q0.w));
    s0 = fmaf(da0, v0, s0);
    s1 = fmaf(da1, v1, s1);
    s2 = fmaf(da2, v2, s2);
    s3 = fmaf(da3, v3, s3);
    float dot = da0*h0*g0 + da1*h1*g1 + da2*h2*g2 + da3*h3*g3;
#pragma unroll
    for (int off = 16; off > 0; off >>= 1) dot += __shfl_down(dot, off, 32);
    if (l32 == 0) ddslot[j] += dot;
  }
  s0 += __shfl_xor(s0, 32, 64);
  s1 += __shfl_xor(s1, 32, 64);
  s2 += __shfl_xor(s2, 32, 64);
  s3 += __shfl_xor(s3, 32, 64);
  if (half == 0)
    *(float4*)(dhx + (size_t)a * HD + ch) = make_float4(s0, s1, s2, s3);
}

// ------------------------------------------------------------------
// fused head (64-row): s = h4@hw1+hb1; ea = ssp(s)@hw2+hb2;
// gh = (sigm(s)*hw2) @ hw1^T
// ------------------------------------------------------------------
__global__ __launch_bounds__(256) void headf_k(
    const float* __restrict__ h4, const float* __restrict__ hw1,
    const float* __restrict__ hb1, const float* __restrict__ hw2,
    const float* __restrict__ hb2, float* __restrict__ ea,
    float* __restrict__ gh)
{
  __shared__ float As[16][68];
  __shared__ float Bs[16][144];
  __shared__ float Ss[64][68];
  __shared__ float red[64][17];
  int t = threadIdx.x;
  int tx = t & 15, ty = t >> 4;
  int m0 = blockIdx.x * 64;

  float acc4[4][4];
#pragma unroll
  for (int r = 0; r < 4; r++)
#pragma unroll
    for (int c = 0; c < 4; c++) acc4[r][c] = 0.0f;

  for (int k0 = 0; k0 < HD; k0 += 16) {
    {
      int rrow = t >> 2;
      int kg = (t & 3) * 4;
      int gm = m0 + rrow;
      float4 av = make_float4(0.f, 0.f, 0.f, 0.f);
      if (gm < N_ATOMS) av = *(const float4*)(h4 + (size_t)gm * HD + k0 + kg);
      As[kg+0][rrow] = av.x; As[kg+1][rrow] = av.y;
      As[kg+2][rrow] = av.z; As[kg+3][rrow] = av.w;
    }
    {
      int kk = t >> 4;
      int n4 = (t & 15) * 4;
      float4 bv = *(const float4*)(hw1 + (size_t)(k0 + kk) * 64 + n4);
      *(float4*)&Bs[kk][n4] = bv;
    }
    __syncthreads();
#pragma unroll
    for (int kk = 0; kk < 16; kk++) {
      float a[4], b[4];
#pragma unroll
      for (int r = 0; r < 4; r++) a[r] = As[kk][ty * 4 + r];
#pragma unroll
      for (int c = 0; c < 4; c++) b[c] = Bs[kk][tx * 4 + c];
#pragma unroll
      for (int r = 0; r < 4; r++)
#pragma unroll
        for (int c = 0; c < 4; c++) acc4[r][c] = fmaf(a[r], b[c], acc4[r][c]);
    }
    __syncthreads();
  }

  {
    int n0 = tx * 4;
    float b1v[4], w2v[4];
#pragma unroll
    for (int c = 0; c < 4; c++) { b1v[c] = hb1[n0 + c]; w2v[c] = hw2[n0 + c]; }
#pragma unroll
    for (int r = 0; r < 4; r++) {
      int lr = ty * 4 + r;
      float p = 0.0f;
#pragma unroll
      for (int c = 0; c < 4; c++) {
        float x = acc4[r][c] + b1v[c];
        p += sspf(x) * w2v[c];
        Ss[lr][n0 + c] = sigmf(x) * w2v[c];
      }
      red[lr][tx] = p;
    }
  }
  __syncthreads();
  if (t < 64) {
    int gm = m0 + t;
    if (gm < N_ATOMS) {
      float s = hb2[0];
#pragma unroll
      for (int j = 0; j < 16; j++) s += red[t][j];
      ea[gm] = s;
    }
  }

  float acc[4][8];
#pragma unroll
  for (int r = 0; r < 4; r++)
#pragma unroll
    for (int c = 0; c < 8; c++) acc[r][c] = 0.0f;

  for (int j0 = 0; j0 < 64; j0 += 16) {
#pragma unroll
    for (int it = 0; it < 2; it++) {
      int idx = t + it * 256;
      int n = idx >> 2;
      int jg = (idx & 3) * 4;
      float4 bv = *(const float4*)(hw1 + (size_t)n * 64 + j0 + jg);
      int pn = BP(n);
      Bs[jg+0][pn] = bv.x; Bs[jg+1][pn] = bv.y;
      Bs[jg+2][pn] = bv.z; Bs[jg+3][pn] = bv.w;
    }
    __syncthreads();
    int p0 = BP(tx * 8);
#pragma unroll
    for (int kk = 0; kk < 16; kk++) {
      float a[4], b[8];
#pragma unroll
      for (int r = 0; r < 4; r++) a[r] = Ss[ty * 4 + r][j0 + kk];
#pragma unroll
      for (int c = 0; c < 8; c++) b[c] = Bs[kk][p0 + c];
#pragma unroll
      for (int r = 0; r < 4; r++)
#pragma unroll
        for (int c = 0; c < 8; c++) acc[r][c] = fmaf(a[r], b[c], acc[r][c]);
    }
    __syncthreads();
  }

  int n0 = tx * 8;
#pragma unroll
  for (int r = 0; r < 4; r++) {
    int gm = m0 + ty * 4 + r;
    if (gm >= N_ATOMS) continue;
    *(float4*)(gh + (size_t)gm * HD + n0)     = *(float4*)&acc[r][0];
    *(float4*)(gh + (size_t)gm * HD + n0 + 4) = *(float4*)&acc[r][4];
  }
}

// ------------------------------------------------------------------
// per-molecule energy reduction
// ------------------------------------------------------------------
__global__ __launch_bounds__(64) void ered_k(
    const int* __restrict__ batch, const float* __restrict__ ea,
    float* __restrict__ energy)
{
  int m = blockIdx.x;
  int lo = 0, hi = N_ATOMS;
  while (lo < hi) { int mid = (lo + hi) >> 1; if (batch[mid] < m) lo = mid + 1; else hi = mid; }
  int beg = lo;
  lo = beg; hi = N_ATOMS;
  while (lo < hi) { int mid = (lo + hi) >> 1; if (batch[mid] < m + 1) lo = mid + 1; else hi = mid; }
  int end = lo;
  float s = 0.0f;
  for (int i = beg + threadIdx.x; i < end; i += 64) s += ea[i];
#pragma unroll
  for (int off = 32; off > 0; off >>= 1) s += __shfl_down(s, off, 64);
  if (threadIdx.x == 0) energy[m] = s;
}

// ------------------------------------------------------------------
// force gather: 8 lanes per atom, both CSR directions, no atomics
// ------------------------------------------------------------------
__global__ __launch_bounds__(256) void forceg_k(
    const int* __restrict__ rptr, const int* __restrict__ rother,
    const float* __restrict__ rdist,
    const int* __restrict__ cptr, const int* __restrict__ cother,
    const float* __restrict__ cdist, const int* __restrict__ cslot,
    const float* __restrict__ ddslot, const float* __restrict__ pos,
    float* __restrict__ force)
{
  int idx = blockIdx.x * 256 + threadIdx.x;
  int a = idx >> 3;
  int g = idx & 7;
  if (a >= N_ATOMS) return;
  float px = pos[3*a+0], py = pos[3*a+1], pz = pos[3*a+2];
  float fx = 0.f, fy = 0.f, fz = 0.f;
  int beg = rptr[a], end = rptr[a+1];
  for (int j = beg + g; j < end; j += 8) {
    int o = rother[j];
    float w = ddslot[j] / rdist[j];
    fx -= w * (px - pos[3*o+0]);
    fy -= w * (py - pos[3*o+1]);
    fz -= w * (pz - pos[3*o+2]);
  }
  beg = cptr[a]; end = cptr[a+1];
  for (int j = beg + g; j < end; j += 8) {
    int o = cother[j];
    float w = ddslot[cslot[j]] / cdist[j];
    fx -= w * (px - pos[3*o+0]);
    fy -= w * (py - pos[3*o+1]);
    fz -= w * (pz - pos[3*o+2]);
  }
#pragma unroll
  for (int off = 4; off > 0; off >>= 1) {
    fx += __shfl_down(fx, off, 8);
    fy += __shfl_down(fy, off, 8);
    fz += __shfl_down(fz, off, 8);
  }
  if (g == 0) {
    force[3*a+0] = fx;
    force[3*a+1] = fy;
    force[3*a+2] = fz;
  }
}

// ------------------------------------------------------------------
// host launch
// ------------------------------------------------------------------
static inline int nblk(int m) { return (m + 63) / 64; }

extern "C" void kernel_launch(void* const* d_in, const int* in_sizes, int n_in,
                              void* d_out, int out_size, void* d_ws, size_t ws_size,
                              hipStream_t stream)
{
  const float* pos   = (const float*)d_in[0];
  const int*   z     = (const int*)d_in[1];
  const int*   batch = (const int*)d_in[2];
  const int*   eidx  = (const int*)d_in[3];
  const float* emb   = (const float*)d_in[4];
  const float* mlp_w1 = (const float*)d_in[5];
  const float* mlp_b1 = (const float*)d_in[6];
  const float* mlp_w2 = (const float*)d_in[7];
  const float* mlp_b2 = (const float*)d_in[8];
  const float* lin1_w = (const float*)d_in[9];
  const float* lin2_w = (const float*)d_in[10];
  const float* lin2_b = (const float*)d_in[11];
  const float* blk_w  = (const float*)d_in[12];
  const float* blk_b  = (const float*)d_in[13];
  const float* hw1 = (const float*)d_in[14];
  const float* hb1 = (const float*)d_in[15];
  const float* hw2 = (const float*)d_in[16];
  const float* hb2 = (const float*)d_in[17];

  float* out = (float*)d_out;          // [NMOL] energies ++ [N,3] forces
  float* ws  = (float*)d_ws;

  const int* row = eidx;
  const int* col = eidx + N_EDGES;

  const size_t NH = (size_t)N_ATOMS * HD;
  size_t o = 0;
  float* dist   = ws + o; o += N_EDGES;
  float* ddslot = ws + o; o += N_EDGES;
  int* cptr   = (int*)(ws + o); o += N_ATOMS + 1;
  int* rptr   = (int*)(ws + o); o += N_ATOMS + 1;
  int* cother = (int*)(ws + o); o += N_EDGES;
  int* rother = (int*)(ws + o); o += N_EDGES;
  int* slotof = (int*)(ws + o); o += N_EDGES;
  int* cslot  = (int*)(ws + o); o += N_EDGES;
  float* cdist = ws + o; o += N_EDGES;
  float* rdist = ws + o; o += N_EDGES;
  int* cur0   = (int*)(ws + o); o += N_ATOMS;
  int* cur1   = (int*)(ws + o); o += N_ATOMS;
  float* hxb[4];   // bf16-packed (uint, 64/row)
  for (int i = 0; i < 4; i++) { hxb[i] = ws + o; o += NH; }
  float* vbuf[4];
  for (int i = 0; i < 4; i++) { vbuf[i] = ws + o; o += NH; }
  float* hA  = ws + o; o += NH;
  float* hB  = ws + o; o += NH;       // dv scratch in backward
  float* agg = ws + o; o += NH;
  float* g0b = ws + o; o += NH;
  float* g1b = ws + o; o += NH;
  float* dgb = ws + o; o += NH;

  int NT = 4096;
  while (NT > 128) {
    size_t need = o + (size_t)NLAY * (NT + 1) * HD;
    if (need * sizeof(float) <= ws_size) break;
    NT >>= 1;
  }
  const int NN = NT + 1;
  const float hstep = FCUT / (float)NT;
  const float inv_h = (float)NT / FCUT;
  unsigned* T = (unsigned*)(ws + o); o += (size_t)NLAY * NN * HD;

  hipMemsetAsync(ddslot, 0, N_EDGES * sizeof(float), stream);

  geom_k<<<(N_EDGES + 255) / 256, 256, 0, stream>>>(pos, row, col, dist);

  // ---------------- CSR build ----------------
  {
    const int EB = (N_EDGES + 255) / 256;
    hipMemsetAsync(cur0, 0, N_ATOMS * sizeof(int), stream);
    hipMemsetAsync(cur1, 0, N_ATOMS * sizeof(int), stream);
    hist_k<<<EB, 256, 0, stream>>>(col, cur0);
    hist_k<<<EB, 256, 0, stream>>>(row, cur1);
    scan_k<<<1, 256, 0, stream>>>(cur0, cptr);
    scan_k<<<1, 256, 0, stream>>>(cur1, rptr);
    hipMemcpyAsync(cur0, cptr, N_ATOMS * sizeof(int), hipMemcpyDeviceToDevice, stream);
    hipMemcpyAsync(cur1, rptr, N_ATOMS * sizeof(int), hipMemcpyDeviceToDevice, stream);
    scat_row_k<<<EB, 256, 0, stream>>>(row, col, dist, cur1, rother, rdist, slotof);
    scat_col_k<<<EB, 256, 0, stream>>>(row, col, dist, cur0, cother, cdist, slotof, cslot);
  }

  // ---------------- filter tables ----------------
  {
    const size_t LNH = (size_t)NN * HD;
    float* Anode  = agg;
    float* dAnode = agg + LNH;
    float* t1 = dgb;
    float* u  = g0b;
    float* s  = g1b;
    float* sp = hA;
    nodeA_k<<<((int)LNH + 255) / 256, 256, 0, stream>>>(Anode, dAnode, NN, hstep);
    dim3 gB(nblk(NN), NLAY);
    gemm128b_k<<<gB, 256, 0, stream>>>(Anode, 0, mlp_w1, (size_t)HD*HD,
                                       mlp_b1, HD, t1, LNH, NN);
    gemm128b_k<<<gB, 256, 0, stream>>>(dAnode, 0, mlp_w1, (size_t)HD*HD,
                                       nullptr, 0, u, LNH, NN);
    int tot = (int)(NLAY * LNH);
    nodeact_k<<<(tot + 255) / 256, 256, 0, stream>>>(t1, u, s, sp, tot);
    float* P0 = dgb;
    float* D0 = g0b;
    gemm128b_k<<<gB, 256, 0, stream>>>(s, LNH, mlp_w2, (size_t)HD*HD,
                                       mlp_b2, HD, P0, LNH, NN);
    gemm128b_k<<<gB, 256, 0, stream>>>(sp, LNH, mlp_w2, (size_t)HD*HD,
                                       nullptr, 0, D0, LNH, NN);
    nodecomb_k<<<(tot + 255) / 256, 256, 0, stream>>>(P0, D0, T, NN, hstep);
  }

  h0_k<<<(N_ATOMS * HD + 255) / 256, 256, 0, stream>>>(emb, z, hA);

  const int AB = (N_ATOMS + 3) / 4;
  const dim3 G32(nblk(N_ATOMS), 4);
  const int GB = nblk(N_ATOMS);

  // ---------------- forward ----------------
  float* hcur = hA;
  float* hnxt = hB;
  for (int i = 0; i < NLAY; i++) {
    const float* l1 = lin1_w + (size_t)i * HD * HD;
    const float* l2 = lin2_w + (size_t)i * HD * HD;
    const float* l2b = lin2_b + (size_t)i * HD;
    const float* bw = blk_w + (size_t)i * HD * HD;
    const float* bb = blk_b + (size_t)i * HD;
    const unsigned* Tl = T + (size_t)i * NN * HD;

    // hx = h @ l1 (bf16 out)
    gemm32_k<0,0,false,true><<<G32, 256, 0, stream>>>(hcur, l1, nullptr, nullptr, hxb[i], N_ATOMS);
    gath_fwd_k<<<AB, 256, 0, stream>>>(cptr, cother, cdist, Tl, (const unsigned*)hxb[i], agg, inv_h);
    // V = agg @ l2 + l2b
    gemm32_k<0,0,false,false><<<G32, 256, 0, stream>>>(agg, l2, l2b, nullptr, vbuf[i], N_ATOMS);
    // h' = ssp(V) @ bw + bb + h
    gemm32_k<1,1,false,false><<<G32, 256, 0, stream>>>(vbuf[i], bw, bb, hcur, hnxt, N_ATOMS);
    float* tmp = hcur; hcur = hnxt; hnxt = tmp;
  }

  // ---------------- head + per-molecule energy ----------------
  float* ea = dgb;
  headf_k<<<GB, 256, 0, stream>>>(hcur, hw1, hb1, hw2, hb2, ea, g0b);
  ered_k<<<NMOL, 64, 0, stream>>>(batch, ea, out);

  // ---------------- backward ----------------
  float* dv = hnxt;    // free buffer (hA/hB not holding h4)
  float* gcur = g0b;
  float* gnxt = g1b;
  for (int i = NLAY - 1; i >= 0; i--) {
    const float* l1 = lin1_w + (size_t)i * HD * HD;
    const float* l2 = lin2_w + (size_t)i * HD * HD;
    const float* bw = blk_w + (size_t)i * HD * HD;
    const unsigned* Tl = T + (size_t)i * NN * HD;

    // dv = (g @ bw^T) * sigm(v)
    gemm32_k<0,2,true,false><<<G32, 256, 0, stream>>>(gcur, bw, nullptr, vbuf[i], dv, N_ATOMS);
    // dagg = dv @ l2^T (bf16 out)
    gemm32_k<0,0,true,true><<<G32, 256, 0, stream>>>(dv, l2, nullptr, nullptr, dgb, N_ATOMS);
    gath_bwd_k<<<AB, 256, 0, stream>>>(rptr, rother, rdist, Tl, (const unsigned*)dgb,
                                       (const unsigned*)hxb[i], agg, ddslot, inv_h);
    if (i > 0) {
      // dh = dhx @ l1^T + g
      gemm32_k<0,1,true,false><<<G32, 256, 0, stream>>>(agg, l1, nullptr, gcur, gnxt, N_ATOMS);
      float* tmp = gcur; gcur = gnxt; gnxt = tmp;
    }
  }

  forceg_k<<<(N_ATOMS * 8 + 255) / 256, 256, 0, stream>>>(
      rptr, rother, rdist, cptr, cother, cdist, cslot, ddslot, pos, out + NMOL);
}